// Round 2
// baseline (184.007 us; speedup 1.0000x reference)
//
#include <hip/hip_runtime.h>
#include <stdint.h>

typedef float  f32x4 __attribute__((ext_vector_type(4)));
typedef short  s16x8 __attribute__((ext_vector_type(8)));
typedef unsigned short u16;

#define BB 2
#define NN 1024
#define HH 64
#define DD 32
#define KK 32768   /* NN*DD */

__device__ __forceinline__ u16 f2bf_rn(float f) {
  uint32_t u = __float_as_uint(f);
  u += 0x7fffu + ((u >> 16) & 1u);
  return (u16)(u >> 16);
}
__device__ __forceinline__ float bf2f(u16 h) {
  return __uint_as_float(((uint32_t)h) << 16);
}

// ---------------------------------------------------------------------------
// Kernel A: g_t[b][c][k] = x[b,s,c] * W[d,c], k = s*32+d, split into bf16 hi/lo.
// 524288 threads, each produces 8 consecutive k (one 16B hi store + one lo).
// ---------------------------------------------------------------------------
__global__ void build_g(const float* __restrict__ x, const float* __restrict__ W,
                        u16* __restrict__ ghi, u16* __restrict__ glo) {
  int t  = blockIdx.x * 256 + threadIdx.x;
  int k0 = (t & 4095) << 3;        // 0..32760, step 8 (stays within one s-block)
  int c  = (t >> 12) & 63;
  int b  = t >> 18;
  int s  = k0 >> 5;
  int d0 = k0 & 31;
  float xv = x[(((b << 10) + s) << 6) + c];
  s16x8 vh, vl;
#pragma unroll
  for (int i = 0; i < 8; ++i) {
    float g = xv * W[((d0 + i) << 6) + c];
    u16 h = f2bf_rn(g);
    vh[i] = (short)h;
    vl[i] = (short)f2bf_rn(g - bf2f(h));
  }
  size_t off = (((size_t)((b << 6) + c)) << 15) + (size_t)k0;
  *reinterpret_cast<s16x8*>(ghi + off) = vh;
  *reinterpret_cast<s16x8*>(glo + off) = vl;
}

// ---------------------------------------------------------------------------
// Kernel B: split-K GEMM  a[b] = kb[b] (1024 x 32768) @ g[b] (32768 x 64)
// using split-precision bf16 MFMA (hi*hi + lo*hi + hi*lo), fp32 accumulate.
// Grid (16 m-tiles, Sk k-chunks, 2 batches), 256 threads = 4 waves.
// Wave w owns rows [mt*64 + w*16, +16), all 64 cols. A loaded fp32 from HBM,
// converted in-reg; B fragments loaded from L2/L3-resident g_t.
// ---------------------------------------------------------------------------
__global__ __launch_bounds__(256, 4) void gemm_split(
    const float* __restrict__ kb, const u16* __restrict__ ghi,
    const u16* __restrict__ glo, float* __restrict__ part,
    int Sk, int Kc) {
  const int w  = threadIdx.x >> 6;
  const int l  = threadIdx.x & 63;
  const int lr = l & 15;           // row-in-frag / col-in-frag
  const int lk = l >> 4;           // k-group 0..3
  const int mt = blockIdx.x;       // 0..15
  const int ks = blockIdx.y;       // 0..Sk-1
  const int b  = blockIdx.z;       // 0..1

  const int row = (mt << 6) + (w << 4) + lr;           // 0..1023
  const size_t k0 = (size_t)ks * (size_t)Kc;

  const float* ap  = kb  + ((((size_t)(b << 10) + row) << 15)) + k0 + (size_t)(lk << 3);
  const u16*   bp  = ghi + (((size_t)((b << 6) + lr)) << 15) + k0 + (size_t)(lk << 3);
  const u16*   bpl = glo + (((size_t)((b << 6) + lr)) << 15) + k0 + (size_t)(lk << 3);

  f32x4 acc[4] = {f32x4{0,0,0,0}, f32x4{0,0,0,0}, f32x4{0,0,0,0}, f32x4{0,0,0,0}};

#pragma unroll 2
  for (int kk = 0; kk < Kc; kk += 32) {
    f32x4 a0 = *reinterpret_cast<const f32x4*>(ap);
    f32x4 a1 = *reinterpret_cast<const f32x4*>(ap + 4);
    ap += 32;
    s16x8 bh[4], bl[4];
#pragma unroll
    for (int ct = 0; ct < 4; ++ct) {
      bh[ct] = *reinterpret_cast<const s16x8*>(bp  + ((size_t)ct << 19)); // ct*16*32768
      bl[ct] = *reinterpret_cast<const s16x8*>(bpl + ((size_t)ct << 19));
    }
    bp += 32; bpl += 32;

    s16x8 ah, al;
#pragma unroll
    for (int i = 0; i < 8; ++i) {
      float f = (i < 4) ? a0[i] : a1[i - 4];
      u16 h = f2bf_rn(f);
      ah[i] = (short)h;
      al[i] = (short)f2bf_rn(f - bf2f(h));
    }
#pragma unroll
    for (int ct = 0; ct < 4; ++ct) {
      acc[ct] = __builtin_amdgcn_mfma_f32_16x16x32_bf16(ah, bh[ct], acc[ct], 0, 0, 0);
      acc[ct] = __builtin_amdgcn_mfma_f32_16x16x32_bf16(al, bh[ct], acc[ct], 0, 0, 0);
      acc[ct] = __builtin_amdgcn_mfma_f32_16x16x32_bf16(ah, bl[ct], acc[ct], 0, 0, 0);
    }
  }

  // partials: part[((b*Sk + ks)*1024 + r)*64 + c]
  float* pb = part + (((size_t)(b * Sk + ks)) << 16);
#pragma unroll
  for (int ct = 0; ct < 4; ++ct) {
#pragma unroll
    for (int i = 0; i < 4; ++i) {
      int rr = (mt << 6) + (w << 4) + (lk << 2) + i;  // D row = (l>>4)*4 + i
      int cc = (ct << 4) + lr;                        // D col = lane&15
      pb[((size_t)rr << 6) + cc] = acc[ct][i];
    }
  }
}

// ---------------------------------------------------------------------------
// Kernel C: per (b,r): reduce Sk partials + conv_bias -> LayerNorm -> MLP.
// One block (256 thr) per row. h = gelu_tanh(n @ W1 + b1); out = h @ W2 + b2.
// ---------------------------------------------------------------------------
__device__ __forceinline__ float gelu_tanh(float v) {
  float u = 0.7978845608028654f * (v + 0.044715f * v * v * v);
  float e = __expf(2.0f * u);
  float th = 1.0f - 2.0f / (e + 1.0f);
  return 0.5f * v * (1.0f + th);
}

__global__ __launch_bounds__(256) void epilogue(
    const float* __restrict__ part, const float* __restrict__ conv_bias,
    const float* __restrict__ ln_scale, const float* __restrict__ ln_bias,
    const float* __restrict__ W1, const float* __restrict__ b1,
    const float* __restrict__ W2, const float* __restrict__ b2,
    float* __restrict__ out, int Sk) {
  __shared__ float red[4][64];
  __shared__ float nbuf[64];
  __shared__ float hbuf[256];

  const int tid = threadIdx.x;
  const int b = blockIdx.x >> 10;
  const int r = blockIdx.x & 1023;
  const int c = tid & 63;
  const int q = tid >> 6;

  // 1) reduce split-K partials
  float s = 0.0f;
  for (int ks = q; ks < Sk; ks += 4)
    s += part[(((size_t)(b * Sk + ks)) << 16) + ((size_t)r << 6) + c];
  red[q][c] = s;
  __syncthreads();

  // 2) LayerNorm on wave 0 (lanes 0..63 hold channel c)
  if (q == 0) {
    float a = red[0][c] + red[1][c] + red[2][c] + red[3][c] + conv_bias[c];
    float sum = a;
#pragma unroll
    for (int off = 32; off >= 1; off >>= 1) sum += __shfl_xor(sum, off);
    float mu = sum * (1.0f / 64.0f);
    float d = a - mu;
    float ss = d * d;
#pragma unroll
    for (int off = 32; off >= 1; off >>= 1) ss += __shfl_xor(ss, off);
    float var = ss * (1.0f / 64.0f);
    nbuf[c] = d * rsqrtf(var + 1e-6f) * ln_scale[c] + ln_bias[c];
  }
  __syncthreads();

  // 3) h[j] = gelu(n @ W1 + b1), j = tid (256 outputs)
  {
    float acc = b1[tid];
#pragma unroll 8
    for (int cc = 0; cc < 64; ++cc) acc += nbuf[cc] * W1[(cc << 8) + tid];
    hbuf[tid] = gelu_tanh(acc);
  }
  __syncthreads();

  // 4) out[c] = h @ W2 + b2 : wave q covers j in [q*64, q*64+64)
  {
    float po = 0.0f;
#pragma unroll 8
    for (int jj = 0; jj < 64; ++jj) {
      int j = (q << 6) + jj;
      po += hbuf[j] * W2[(j << 6) + c];
    }
    red[q][c] = po;
  }
  __syncthreads();
  if (tid < 64) {
    float o = red[0][c] + red[1][c] + red[2][c] + red[3][c] + b2[c];
    out[(((size_t)(b << 10) + r) << 6) + c] = o;
  }
}

// ---------------------------------------------------------------------------
extern "C" void kernel_launch(void* const* d_in, const int* in_sizes, int n_in,
                              void* d_out, int out_size, void* d_ws, size_t ws_size,
                              hipStream_t stream) {
  const float* x         = (const float*)d_in[0];
  const float* kb        = (const float*)d_in[1];
  const float* kernel_W  = (const float*)d_in[2];
  const float* conv_bias = (const float*)d_in[3];
  const float* ln_scale  = (const float*)d_in[4];
  const float* ln_bias   = (const float*)d_in[5];
  const float* W1        = (const float*)d_in[6];
  const float* b1        = (const float*)d_in[7];
  const float* W2        = (const float*)d_in[8];
  const float* b2        = (const float*)d_in[9];
  float* out = (float*)d_out;

  char* wsb = (char*)d_ws;
  u16* ghi = (u16*)wsb;                               // 8,388,608 B
  u16* glo = (u16*)(wsb + 8388608);                   // 8,388,608 B
  float* part = (float*)(wsb + 16777216);             // Sk * 524,288 B

  // pick largest split-K that fits the workspace (deterministic in ws_size)
  int Sk = 32;
  while (Sk > 1 && 16777216ull + (size_t)Sk * 524288ull > ws_size) Sk >>= 1;
  int Kc = KK / Sk;

  build_g<<<2048, 256, 0, stream>>>(x, kernel_W, ghi, glo);
  gemm_split<<<dim3(16, Sk, 2), 256, 0, stream>>>(kb, ghi, glo, part, Sk, Kc);
  epilogue<<<dim3(2048), 256, 0, stream>>>(part, conv_bias, ln_scale, ln_bias,
                                           W1, b1, W2, b2, out, Sk);
}